// Round 10
// baseline (244.723 us; speedup 1.0000x reference)
//
#include <hip/hip_runtime.h>
#include <hip/hip_bf16.h>

#define NSUBJ 64
#define CIN   295
#define DD    270
#define TT    2048
#define BB    128

// Wf tiled layout: [s][ks:10][kq:4][m:288][k8:8]  (bf16, c = ks*32+kq*8+k8)
// column c==295 holds the fused bias (Ws@b1); B-side c==295 synthesized as 1.0
#define WF_PER_S  92160   // 10*4*288*8
#define WF_PER_KS 9216    // 4*288*8
// W1t tiled layout: [ks:9][kq:4][c:320][8] bf16 (d = ks*32+kq*8+k8), c=295 -> b1
#define W1T_PER_KS 10240  // 4*320*8

typedef __attribute__((ext_vector_type(8))) short bf16x8;
typedef __attribute__((ext_vector_type(4))) float f32x4;
typedef unsigned short u16;

__device__ __forceinline__ u16 f2bf(float f) {
    return __bfloat16_as_ushort(__float2bfloat16(f));   // RNE HW cvt
}

// async global->LDS, 16B/lane; lds dest = base + lane*16 (linear, wave-uniform base)
__device__ __forceinline__ void glds16(const void* g, void* lds_base) {
    __builtin_amdgcn_global_load_lds(
        (const __attribute__((address_space(1))) unsigned int*)g,
        (__attribute__((address_space(3))) unsigned int*)lds_base, 16, 0, 0);
}

// ---------------------------------------------------------------------------
// W1 [270][295] f32 (+ b1 as c=295) -> W1t bf16 tiled [ks][kq][c:320][8]
// ---------------------------------------------------------------------------
__global__ __launch_bounds__(256) void k_prep_w1(const float* __restrict__ W1,
                                                 const float* __restrict__ b1,
                                                 u16* __restrict__ W1t)
{
    const int idx = blockIdx.x * 256 + threadIdx.x;      // 92160 total
    const int ks = idx / W1T_PER_KS;
    const int r  = idx - ks * W1T_PER_KS;
    const int kq = r / 2560;
    const int c  = (r - kq * 2560) >> 3;   // 0..319
    const int k8 = r & 7;
    const int d  = ks * 32 + kq * 8 + k8;
    float v = 0.f;
    if (d < DD) {
        if (c < CIN) v = W1[d * CIN + c];
        else if (c == CIN) v = b1[d];
    }
    W1t[idx] = f2bf(v);
}

// ---------------------------------------------------------------------------
// Wf[s] = bf16(Ws[s] @ [W1|b1]) in k_main's tiled A layout
// grid (3 mt, 64 s), block 256 = 4 waves (2M x 2N), tile 96e x 320c, K=288
// ---------------------------------------------------------------------------
__global__ __launch_bounds__(256, 1) void k_fuse_w(const float* __restrict__ Ws,
                                                   const u16* __restrict__ W1t,
                                                   u16* __restrict__ Wf)
{
    __shared__ u16 Aw[3072];    // [kq:4][96][8]
    __shared__ u16 Bw[10240];   // [kq:4][320][8]
    const int tid = threadIdx.x, lane = tid & 63, wid = tid >> 6;
    const int wm = wid >> 1, wn = wid & 1;
    const int mt = blockIdx.x, s = blockIdx.y;
    const int e0 = mt * 96;
    const float* Wsb = Ws + (size_t)s * DD * DD;

    f32x4 acc[3][10];
#pragma unroll
    for (int i = 0; i < 3; ++i)
#pragma unroll
        for (int j = 0; j < 10; ++j) acc[i][j] = (f32x4){0.f, 0.f, 0.f, 0.f};

    for (int ks = 0; ks < 9; ++ks) {
        const int k0 = ks * 32;
#pragma unroll
        for (int ci = 0; ci < 3; ++ci) {
            const int id = tid + ci * 256;
            const int m = id >> 3, q = id & 7;
            const int e = e0 + m, d = k0 + q * 4;
            float2 v01 = {0.f, 0.f}, v23 = {0.f, 0.f};
            if (e < DD) {
                if (d < DD)     v01 = *(const float2*)(Wsb + (size_t)e * DD + d);
                if (d + 2 < DD) v23 = *(const float2*)(Wsb + (size_t)e * DD + d + 2);
            }
            ushort4 h;
            h.x = f2bf(v01.x); h.y = f2bf(v01.y); h.z = f2bf(v23.x); h.w = f2bf(v23.y);
            *(ushort4*)(&Aw[(q >> 1) * 768 + m * 8 + (q & 1) * 4]) = h;
        }
#pragma unroll
        for (int k5 = 0; k5 < 5; ++k5) {
            const int seg = wid * 5 + k5;
            glds16(W1t + (size_t)ks * W1T_PER_KS + seg * 512 + lane * 8, &Bw[seg * 512]);
        }
        __syncthreads();
        bf16x8 af[3];
#pragma unroll
        for (int i = 0; i < 3; ++i)
            af[i] = *(const bf16x8*)(&Aw[(lane >> 4) * 768 + (wm * 48 + i * 16 + (lane & 15)) * 8]);
#pragma unroll
        for (int j = 0; j < 10; ++j) {
            const bf16x8 bfj = *(const bf16x8*)(&Bw[(lane >> 4) * 2560 + (wn * 160 + j * 16 + (lane & 15)) * 8]);
#pragma unroll
            for (int i = 0; i < 3; ++i)
                acc[i][j] = __builtin_amdgcn_mfma_f32_16x16x32_bf16(af[i], bfj, acc[i][j], 0, 0, 0);
        }
        __syncthreads();
    }
    const int rb = (lane >> 4) * 4, cc = lane & 15;
#pragma unroll
    for (int i = 0; i < 3; ++i) {
#pragma unroll
        for (int r = 0; r < 4; ++r) {
            const int e = e0 + wm * 48 + i * 16 + rb + r;
#pragma unroll
            for (int j = 0; j < 10; ++j) {
                const int c = wn * 160 + j * 16 + cc;
                Wf[(size_t)s * WF_PER_S + (c >> 5) * WF_PER_KS + ((c >> 3) & 3) * 2304
                   + e * 8 + (c & 7)] = f2bf(acc[i][j][r]);
            }
        }
    }
}

// ---------------------------------------------------------------------------
// out[b] = Wf[subj[b]] @ [X[b]; 1]
// LDS-FREE, BARRIER-FREE dataflow kernel.
// grid 4096 (XCD-chunked: 512 blocks/XCD, 16 consecutive b per XCD -> Wf in L2)
// block 256 = 4 waves (2M x 2N), tile 288e x 64t, K=320, fully unrolled.
// A-frags: direct 16B loads from tiled Wf (L2/L3-resident).
// B-frags: 16 scalar f32 X loads/lane/step (4x64B segments/instr) + in-reg cvt.
// Compiler schedules loads across MFMAs freely; launch_bounds(256,2) = 256-reg
// cap, no spill.
// ---------------------------------------------------------------------------
__global__ __launch_bounds__(256, 2) void k_main(const float* __restrict__ X,
                                                 const int* __restrict__ subj,
                                                 const u16* __restrict__ Wf,
                                                 float* __restrict__ out)
{
    const int tid = threadIdx.x, lane = tid & 63, wid = tid >> 6;
    const int wm = wid >> 1, wn = wid & 1;
    const int g = lane >> 4, l15 = lane & 15;
    // bijective XCD chunk swizzle: 4096 blocks, 512 per XCD, (b,nt) nt-fastest
    const int hw = blockIdx.x;
    const int w  = (hw & 7) * 512 + (hw >> 3);
    const int b  = w >> 5, nt = w & 31;
    const int t0 = nt * 64;
    const int s  = subj[b];
    const float* Xb = X + (size_t)b * CIN * TT;
    // per-lane A base: element (g*2304 + (wm*144 + l15)*8); i adds i*128 el
    const u16* aB = Wf + (size_t)s * WF_PER_S + g * 2304 + (wm * 144 + l15) * 8;
    // per-lane X t-columns
    const int tj0 = t0 + wn * 32 + l15;

    f32x4 acc[9][2];
#pragma unroll
    for (int i = 0; i < 9; ++i)
#pragma unroll
        for (int j = 0; j < 2; ++j) acc[i][j] = (f32x4){0.f, 0.f, 0.f, 0.f};

#pragma unroll
    for (int ks = 0; ks < 9; ++ks) {           // c = ks*32+g*8+q <= 287 < 295
        bf16x8 af[9];
#pragma unroll
        for (int i = 0; i < 9; ++i)
            af[i] = *(const bf16x8*)(aB + (size_t)ks * WF_PER_KS + i * 128);
        float x0[8], x1[8];
#pragma unroll
        for (int q = 0; q < 8; ++q) {
            const size_t roff = (size_t)((ks * 32 + g * 8 + q)) * TT + tj0;
            x0[q] = Xb[roff];
            x1[q] = Xb[roff + 16];
        }
        bf16x8 b0, b1;
#pragma unroll
        for (int q = 0; q < 8; ++q) {
            b0[q] = (short)f2bf(x0[q]);
            b1[q] = (short)f2bf(x1[q]);
        }
#pragma unroll
        for (int i = 0; i < 9; ++i) {
            acc[i][0] = __builtin_amdgcn_mfma_f32_16x16x32_bf16(af[i], b0, acc[i][0], 0, 0, 0);
            acc[i][1] = __builtin_amdgcn_mfma_f32_16x16x32_bf16(af[i], b1, acc[i][1], 0, 0, 0);
        }
    }
    // ---- tail ks=9: c = 288+g*8+q; c==295 -> 1.0, c>295 -> 0 ----
    {
        bf16x8 af[9];
#pragma unroll
        for (int i = 0; i < 9; ++i)
            af[i] = *(const bf16x8*)(aB + (size_t)9 * WF_PER_KS + i * 128);
        bf16x8 b0, b1;
#pragma unroll
        for (int q = 0; q < 8; ++q) {
            const int c  = 288 + g * 8 + q;
            const int cl = (c < CIN) ? c : (c - 33);      // all in-bounds
            const size_t roff = (size_t)cl * TT + tj0;
            const float v0 = Xb[roff];
            const float v1 = Xb[roff + 16];
            float w0, w1;
            if (g == 0) {
                w0 = (q == 7) ? 1.0f : v0;
                w1 = (q == 7) ? 1.0f : v1;
            } else {
                w0 = 0.0f; w1 = 0.0f;
            }
            b0[q] = (short)f2bf(w0);
            b1[q] = (short)f2bf(w1);
        }
#pragma unroll
        for (int i = 0; i < 9; ++i) {
            acc[i][0] = __builtin_amdgcn_mfma_f32_16x16x32_bf16(af[i], b0, acc[i][0], 0, 0, 0);
            acc[i][1] = __builtin_amdgcn_mfma_f32_16x16x32_bf16(af[i], b1, acc[i][1], 0, 0, 0);
        }
    }

    // epilogue: C/D layout col=lane&15, row=(lane>>4)*4+reg (bias fused in K)
    const int rb = g * 4;
#pragma unroll
    for (int i = 0; i < 9; ++i) {
#pragma unroll
        for (int r = 0; r < 4; ++r) {
            const int e = wm * 144 + i * 16 + rb + r;
            if (e < DD) {
#pragma unroll
                for (int j = 0; j < 2; ++j) {
                    const int t = tj0 + j * 16;
                    out[((size_t)b * DD + e) * TT + t] = acc[i][j][r];
                }
            }
        }
    }
}

extern "C" void kernel_launch(void* const* d_in, const int* in_sizes, int n_in,
                              void* d_out, int out_size, void* d_ws, size_t ws_size,
                              hipStream_t stream) {
    const float* X    = (const float*)d_in[0];
    const int*   subj = (const int*)d_in[1];
    const float* W1   = (const float*)d_in[2];
    const float* b1   = (const float*)d_in[3];
    const float* Ws   = (const float*)d_in[4];
    float* out = (float*)d_out;

    u16* Wf  = (u16*)d_ws;                                         // 11,796,480 B
    u16* W1t = (u16*)((char*)d_ws + (size_t)NSUBJ * WF_PER_S * 2); // + 184,320 B

    k_prep_w1<<<dim3(360), 256, 0, stream>>>(W1, b1, W1t);
    k_fuse_w<<<dim3(3, NSUBJ), 256, 0, stream>>>(Ws, W1t, Wf);
    k_main<<<dim3(TT / 64 * BB), 256, 0, stream>>>(X, subj, Wf, out);
}

// Round 11
// 184.820 us; speedup vs baseline: 1.3241x; 1.3241x over previous
//
#include <hip/hip_runtime.h>
#include <hip/hip_bf16.h>

#define NSUBJ 64
#define CIN   295
#define DD    270
#define TT    2048
#define BB    128

// Wf tiled layout: [s][ks:10][kq:4][m:288][k8:8]  (bf16, c = ks*32+kq*8+k8)
// column c==295 holds the fused bias (Ws@b1); B-side c==295 synthesized as 1.0
#define WF_PER_S  92160   // 10*4*288*8
#define WF_PER_KS 9216    // 4*288*8
// W1t tiled layout: [ks:9][kq:4][c:320][8] bf16 (d = ks*32+kq*8+k8), c=295 -> b1
#define W1T_PER_KS 10240  // 4*320*8

typedef __attribute__((ext_vector_type(8))) short bf16x8;
typedef __attribute__((ext_vector_type(4))) float f32x4;
typedef unsigned short u16;

__device__ __forceinline__ u16 f2bf(float f) {
    return __bfloat16_as_ushort(__float2bfloat16(f));   // RNE HW cvt
}

// async global->LDS, 16B/lane; lds dest = base + lane*16 (linear, wave-uniform base)
__device__ __forceinline__ void glds16(const void* g, void* lds_base) {
    __builtin_amdgcn_global_load_lds(
        (const __attribute__((address_space(1))) unsigned int*)g,
        (__attribute__((address_space(3))) unsigned int*)lds_base, 16, 0, 0);
}

#define WAITV(N) asm volatile("s_waitcnt vmcnt(" #N ")" ::: "memory")
#define BAR()    __builtin_amdgcn_s_barrier()
#define SB()     __builtin_amdgcn_sched_barrier(0)

// ---------------------------------------------------------------------------
// W1 [270][295] f32 (+ b1 as c=295) -> W1t bf16 tiled [ks][kq][c:320][8]
// ---------------------------------------------------------------------------
__global__ __launch_bounds__(256) void k_prep_w1(const float* __restrict__ W1,
                                                 const float* __restrict__ b1,
                                                 u16* __restrict__ W1t)
{
    const int idx = blockIdx.x * 256 + threadIdx.x;      // 92160 total
    const int ks = idx / W1T_PER_KS;
    const int r  = idx - ks * W1T_PER_KS;
    const int kq = r / 2560;
    const int c  = (r - kq * 2560) >> 3;   // 0..319
    const int k8 = r & 7;
    const int d  = ks * 32 + kq * 8 + k8;
    float v = 0.f;
    if (d < DD) {
        if (c < CIN) v = W1[d * CIN + c];
        else if (c == CIN) v = b1[d];
    }
    W1t[idx] = f2bf(v);
}

// ---------------------------------------------------------------------------
// Wf[s] = bf16(Ws[s] @ [W1|b1]) in k_main's tiled A layout
// grid (3 mt, 64 s), block 256 = 4 waves (2M x 2N), tile 96e x 320c, K=288
// ---------------------------------------------------------------------------
__global__ __launch_bounds__(256, 1) void k_fuse_w(const float* __restrict__ Ws,
                                                   const u16* __restrict__ W1t,
                                                   u16* __restrict__ Wf)
{
    __shared__ u16 Aw[3072];    // [kq:4][96][8]
    __shared__ u16 Bw[10240];   // [kq:4][320][8]
    const int tid = threadIdx.x, lane = tid & 63, wid = tid >> 6;
    const int wm = wid >> 1, wn = wid & 1;
    const int mt = blockIdx.x, s = blockIdx.y;
    const int e0 = mt * 96;
    const float* Wsb = Ws + (size_t)s * DD * DD;

    f32x4 acc[3][10];
#pragma unroll
    for (int i = 0; i < 3; ++i)
#pragma unroll
        for (int j = 0; j < 10; ++j) acc[i][j] = (f32x4){0.f, 0.f, 0.f, 0.f};

    for (int ks = 0; ks < 9; ++ks) {
        const int k0 = ks * 32;
#pragma unroll
        for (int ci = 0; ci < 3; ++ci) {
            const int id = tid + ci * 256;
            const int m = id >> 3, q = id & 7;
            const int e = e0 + m, d = k0 + q * 4;
            float2 v01 = {0.f, 0.f}, v23 = {0.f, 0.f};
            if (e < DD) {
                if (d < DD)     v01 = *(const float2*)(Wsb + (size_t)e * DD + d);
                if (d + 2 < DD) v23 = *(const float2*)(Wsb + (size_t)e * DD + d + 2);
            }
            ushort4 h;
            h.x = f2bf(v01.x); h.y = f2bf(v01.y); h.z = f2bf(v23.x); h.w = f2bf(v23.y);
            *(ushort4*)(&Aw[(q >> 1) * 768 + m * 8 + (q & 1) * 4]) = h;
        }
#pragma unroll
        for (int k5 = 0; k5 < 5; ++k5) {
            const int seg = wid * 5 + k5;
            glds16(W1t + (size_t)ks * W1T_PER_KS + seg * 512 + lane * 8, &Bw[seg * 512]);
        }
        __syncthreads();
        bf16x8 af[3];
#pragma unroll
        for (int i = 0; i < 3; ++i)
            af[i] = *(const bf16x8*)(&Aw[(lane >> 4) * 768 + (wm * 48 + i * 16 + (lane & 15)) * 8]);
#pragma unroll
        for (int j = 0; j < 10; ++j) {
            const bf16x8 bfj = *(const bf16x8*)(&Bw[(lane >> 4) * 2560 + (wn * 160 + j * 16 + (lane & 15)) * 8]);
#pragma unroll
            for (int i = 0; i < 3; ++i)
                acc[i][j] = __builtin_amdgcn_mfma_f32_16x16x32_bf16(af[i], bfj, acc[i][j], 0, 0, 0);
        }
        __syncthreads();
    }
    const int rb = (lane >> 4) * 4, cc = lane & 15;
#pragma unroll
    for (int i = 0; i < 3; ++i) {
#pragma unroll
        for (int r = 0; r < 4; ++r) {
            const int e = e0 + wm * 48 + i * 16 + rb + r;
#pragma unroll
            for (int j = 0; j < 10; ++j) {
                const int c = wn * 160 + j * 16 + cc;
                Wf[(size_t)s * WF_PER_S + (c >> 5) * WF_PER_KS + ((c >> 3) & 3) * 2304
                   + e * 8 + (c & 7)] = f2bf(acc[i][j][r]);
            }
        }
    }
}

// ---------------------------------------------------------------------------
// out[b] = Wf[subj[b]] @ [X[b]; 1]
// R9 structure (all staging via glds16, X transposed in LDS with source-side
// swizzle) + TRIPLE buffer + counted-vmcnt barrier: stage 2 steps ahead,
// WAITV(n_wave) retires only S(k+1); S(k+2) stays in flight ACROSS the
// barrier -> memory queue never empty.
// grid 4096 XCD-chunked (512/XCD, 16 consecutive b); block 256 = 4 waves.
// Per wave per step glds: A {w0:5,w1:5,w2:4,w3:4} + X 2 => n = {7,7,6,6}.
// ---------------------------------------------------------------------------
__global__ __launch_bounds__(256, 2) void k_main(const float* __restrict__ X,
                                                 const int* __restrict__ subj,
                                                 const u16* __restrict__ Wf,
                                                 float* __restrict__ out)
{
    __shared__ u16   Am[3][9216];    // [kq:4][288][8] bf16, 18KB each
    __shared__ float Xm[3][2048];    // [c:32][t:64] f32 (swizzled), 8KB each
    const int tid = threadIdx.x, lane = tid & 63, wid = tid >> 6;
    const int wm = wid >> 1, wn = wid & 1;
    const int hw = blockIdx.x;                 // 0..4095
    const int w  = (hw & 7) * 512 + (hw >> 3); // bijection, 512 blocks/XCD
    const int b  = w >> 5, nt = w & 31;
    const int t0 = nt * 64;
    const int s = subj[b];
    const float* Xb = X + (size_t)b * CIN * TT;
    const u16* WfA = Wf + (size_t)s * WF_PER_S;
    const int g = lane >> 4;          // kq group 0..3

    f32x4 acc[9][2];
#pragma unroll
    for (int i = 0; i < 9; ++i)
#pragma unroll
        for (int j = 0; j < 2; ++j) acc[i][j] = (f32x4){0.f, 0.f, 0.f, 0.f};

    // A: 18 segs x 1KB; waves 0,1: 5 glds; waves 2,3: 4 glds
#define STAGEA(KS, BUF)                                                     \
    {                                                                       \
        _Pragma("unroll")                                                   \
        for (int k5 = 0; k5 < 5; ++k5) {                                    \
            const int seg = wid + 4 * k5;                                   \
            if (seg < 18)                                                   \
                glds16(WfA + (size_t)(KS) * WF_PER_KS + seg * 512 + lane * 8,\
                       &Am[BUF][seg * 512]);                                \
        }                                                                   \
    }
    // X: 8 segs x 1KB (4 rows of 64 f32); wave w stages segs 2w, 2w+1.
    // Per-lane source col pre-swizzled (16B-chunk XOR); row clamped to <295.
#define STAGEX(KS, BUF)                                                     \
    {                                                                       \
        _Pragma("unroll")                                                   \
        for (int k2 = 0; k2 < 2; ++k2) {                                    \
            const int seg = wid * 2 + k2;                                   \
            const int cr0 = (KS) * 32 + seg * 4 + g;                        \
            const int cr  = (cr0 < CIN) ? cr0 : (CIN - 1);                  \
            const int sc  = (lane & 15) ^ (((seg >> 1) & 3) << 2);          \
            glds16(Xb + (size_t)cr * TT + t0 + sc * 4,                      \
                   &Xm[BUF][seg * 256]);                                    \
        }                                                                   \
    }
    // this wave's per-step glds count as vmcnt immediate
#define WAITSTEP()  { if (wid < 2) WAITV(7); else WAITV(6); }

    // Build 2 B-frags from Xm (transposed read, 2-way banks, bf16 cvt in-reg)
#define COMPUTE(BUF, LAST)                                                  \
    {                                                                       \
        const float* Xc = &Xm[BUF][0];                                      \
        bf16x8 bfr[2];                                                      \
        _Pragma("unroll")                                                   \
        for (int j = 0; j < 2; ++j) {                                       \
            const int tsw = (wn * 32 + j * 16 + (lane & 15)) ^ (g << 4);    \
            bf16x8 bb;                                                      \
            _Pragma("unroll")                                               \
            for (int q = 0; q < 8; ++q) {                                   \
                float v = Xc[(g * 8 + q) * 64 + tsw];                       \
                if (LAST) {                                                 \
                    if (q == 7)      v = (g == 0) ? 1.0f : 0.0f;            \
                    else if (g > 0)  v = 0.0f;                              \
                }                                                           \
                bb[q] = (short)f2bf(v);                                     \
            }                                                               \
            bfr[j] = bb;                                                    \
        }                                                                   \
        _Pragma("unroll")                                                   \
        for (int i = 0; i < 9; ++i) {                                       \
            const bf16x8 af = *(const bf16x8*)(&Am[BUF][g * 2304 + (wm * 144 + i * 16 + (lane & 15)) * 8]); \
            acc[i][0] = __builtin_amdgcn_mfma_f32_16x16x32_bf16(af, bfr[0], acc[i][0], 0, 0, 0); \
            acc[i][1] = __builtin_amdgcn_mfma_f32_16x16x32_bf16(af, bfr[1], acc[i][1], 0, 0, 0); \
        }                                                                   \
    }

    // ---- prologue: issue S0, S1; wait S0 only (S1 crosses the barrier) ----
    STAGEA(0, 0); STAGEX(0, 0); SB();
    STAGEA(1, 1); STAGEX(1, 1); SB();
    WAITSTEP();
    BAR();

    // ---- steady steps k=0..7: issue S(k+2); compute k; wait S(k+1) ----
#define STEP(K)                                                             \
    {                                                                       \
        STAGEA((K) + 2, ((K) + 2) % 3); STAGEX((K) + 2, ((K) + 2) % 3); SB();\
        COMPUTE((K) % 3, 0);                                                \
        WAITSTEP();                                                         \
        BAR();                                                              \
    }
    STEP(0) STEP(1) STEP(2) STEP(3) STEP(4) STEP(5) STEP(6) STEP(7)
    // ---- step 8: nothing left to stage; drain S9 ----
    COMPUTE(2, 0);
    WAITV(0);
    BAR();
    // ---- step 9 (bias/pad column handled in-register) ----
    COMPUTE(0, 1);

    // epilogue: C/D layout col=lane&15, row=(lane>>4)*4+reg (bias fused in K)
    const int rb = g * 4, cc = lane & 15;
#pragma unroll
    for (int i = 0; i < 9; ++i) {
#pragma unroll
        for (int r = 0; r < 4; ++r) {
            const int e = wm * 144 + i * 16 + rb + r;
            if (e < DD) {
#pragma unroll
                for (int j = 0; j < 2; ++j) {
                    const int t = t0 + wn * 32 + j * 16 + cc;
                    out[((size_t)b * DD + e) * TT + t] = acc[i][j][r];
                }
            }
        }
    }
#undef STAGEA
#undef STAGEX
#undef WAITSTEP
#undef COMPUTE
#undef STEP
}

extern "C" void kernel_launch(void* const* d_in, const int* in_sizes, int n_in,
                              void* d_out, int out_size, void* d_ws, size_t ws_size,
                              hipStream_t stream) {
    const float* X    = (const float*)d_in[0];
    const int*   subj = (const int*)d_in[1];
    const float* W1   = (const float*)d_in[2];
    const float* b1   = (const float*)d_in[3];
    const float* Ws   = (const float*)d_in[4];
    float* out = (float*)d_out;

    u16* Wf  = (u16*)d_ws;                                         // 11,796,480 B
    u16* W1t = (u16*)((char*)d_ws + (size_t)NSUBJ * WF_PER_S * 2); // + 184,320 B

    k_prep_w1<<<dim3(360), 256, 0, stream>>>(W1, b1, W1t);
    k_fuse_w<<<dim3(3, NSUBJ), 256, 0, stream>>>(Ws, W1t, Wf);
    k_main<<<dim3(TT / 64 * BB), 256, 0, stream>>>(X, subj, Wf, out);
}

// Round 12
// 181.718 us; speedup vs baseline: 1.3467x; 1.0171x over previous
//
#include <hip/hip_runtime.h>
#include <hip/hip_bf16.h>

#define NSUBJ 64
#define CIN   295
#define DD    270
#define TT    2048
#define BB    128

// Wf tiled layout: [s][ks:10][kq:4][m:288][k8:8]  (bf16, c = ks*32+kq*8+k8)
// column c==295 holds the fused bias (Ws@b1); B-side c==295 synthesized as 1.0
#define WF_PER_S  92160   // 10*4*288*8
#define WF_PER_KS 9216    // 4*288*8
// W1t tiled layout: [ks:9][kq:4][c:320][8] bf16 (d = ks*32+kq*8+k8), c=295 -> b1
#define W1T_PER_KS 10240  // 4*320*8

typedef __attribute__((ext_vector_type(8))) short bf16x8;
typedef __attribute__((ext_vector_type(4))) float f32x4;
typedef unsigned short u16;

__device__ __forceinline__ u16 f2bf(float f) {
    return __bfloat16_as_ushort(__float2bfloat16(f));   // RNE HW cvt
}

// async global->LDS, 16B/lane; lds dest = base + lane*16 (linear, wave-uniform base)
__device__ __forceinline__ void glds16(const void* g, void* lds_base) {
    __builtin_amdgcn_global_load_lds(
        (const __attribute__((address_space(1))) unsigned int*)g,
        (__attribute__((address_space(3))) unsigned int*)lds_base, 16, 0, 0);
}

#define WAITV(N) asm volatile("s_waitcnt vmcnt(" #N ")" ::: "memory")
#define BAR()    __builtin_amdgcn_s_barrier()
#define SB()     __builtin_amdgcn_sched_barrier(0)

// ---------------------------------------------------------------------------
// W1 [270][295] f32 (+ b1 as c=295) -> W1t bf16 tiled [ks][kq][c:320][8]
// ---------------------------------------------------------------------------
__global__ __launch_bounds__(256) void k_prep_w1(const float* __restrict__ W1,
                                                 const float* __restrict__ b1,
                                                 u16* __restrict__ W1t)
{
    const int idx = blockIdx.x * 256 + threadIdx.x;      // 92160 total
    const int ks = idx / W1T_PER_KS;
    const int r  = idx - ks * W1T_PER_KS;
    const int kq = r / 2560;
    const int c  = (r - kq * 2560) >> 3;   // 0..319
    const int k8 = r & 7;
    const int d  = ks * 32 + kq * 8 + k8;
    float v = 0.f;
    if (d < DD) {
        if (c < CIN) v = W1[d * CIN + c];
        else if (c == CIN) v = b1[d];
    }
    W1t[idx] = f2bf(v);
}

// ---------------------------------------------------------------------------
// Wf[s] = bf16(Ws[s] @ [W1|b1]) in k_main's tiled A layout
// grid (3 mt, 64 s), block 256 = 4 waves (2M x 2N), tile 96e x 320c, K=288
// ---------------------------------------------------------------------------
__global__ __launch_bounds__(256, 1) void k_fuse_w(const float* __restrict__ Ws,
                                                   const u16* __restrict__ W1t,
                                                   u16* __restrict__ Wf)
{
    __shared__ u16 Aw[3072];    // [kq:4][96][8]
    __shared__ u16 Bw[10240];   // [kq:4][320][8]
    const int tid = threadIdx.x, lane = tid & 63, wid = tid >> 6;
    const int wm = wid >> 1, wn = wid & 1;
    const int mt = blockIdx.x, s = blockIdx.y;
    const int e0 = mt * 96;
    const float* Wsb = Ws + (size_t)s * DD * DD;

    f32x4 acc[3][10];
#pragma unroll
    for (int i = 0; i < 3; ++i)
#pragma unroll
        for (int j = 0; j < 10; ++j) acc[i][j] = (f32x4){0.f, 0.f, 0.f, 0.f};

    for (int ks = 0; ks < 9; ++ks) {
        const int k0 = ks * 32;
#pragma unroll
        for (int ci = 0; ci < 3; ++ci) {
            const int id = tid + ci * 256;
            const int m = id >> 3, q = id & 7;
            const int e = e0 + m, d = k0 + q * 4;
            float2 v01 = {0.f, 0.f}, v23 = {0.f, 0.f};
            if (e < DD) {
                if (d < DD)     v01 = *(const float2*)(Wsb + (size_t)e * DD + d);
                if (d + 2 < DD) v23 = *(const float2*)(Wsb + (size_t)e * DD + d + 2);
            }
            ushort4 h;
            h.x = f2bf(v01.x); h.y = f2bf(v01.y); h.z = f2bf(v23.x); h.w = f2bf(v23.y);
            *(ushort4*)(&Aw[(q >> 1) * 768 + m * 8 + (q & 1) * 4]) = h;
        }
#pragma unroll
        for (int k5 = 0; k5 < 5; ++k5) {
            const int seg = wid * 5 + k5;
            glds16(W1t + (size_t)ks * W1T_PER_KS + seg * 512 + lane * 8, &Bw[seg * 512]);
        }
        __syncthreads();
        bf16x8 af[3];
#pragma unroll
        for (int i = 0; i < 3; ++i)
            af[i] = *(const bf16x8*)(&Aw[(lane >> 4) * 768 + (wm * 48 + i * 16 + (lane & 15)) * 8]);
#pragma unroll
        for (int j = 0; j < 10; ++j) {
            const bf16x8 bfj = *(const bf16x8*)(&Bw[(lane >> 4) * 2560 + (wn * 160 + j * 16 + (lane & 15)) * 8]);
#pragma unroll
            for (int i = 0; i < 3; ++i)
                acc[i][j] = __builtin_amdgcn_mfma_f32_16x16x32_bf16(af[i], bfj, acc[i][j], 0, 0, 0);
        }
        __syncthreads();
    }
    const int rb = (lane >> 4) * 4, cc = lane & 15;
#pragma unroll
    for (int i = 0; i < 3; ++i) {
#pragma unroll
        for (int r = 0; r < 4; ++r) {
            const int e = e0 + wm * 48 + i * 16 + rb + r;
#pragma unroll
            for (int j = 0; j < 10; ++j) {
                const int c = wn * 160 + j * 16 + cc;
                Wf[(size_t)s * WF_PER_S + (c >> 5) * WF_PER_KS + ((c >> 3) & 3) * 2304
                   + e * 8 + (c & 7)] = f2bf(acc[i][j][r]);
            }
        }
    }
}

// ---------------------------------------------------------------------------
// out[b] = Wf[subj[b]] @ [X[b]; 1]
// Tile 288e x 128t (A traffic halved vs BN=64), K=320.
// grid 2048 XCD-chunked (256/XCD); block 512 = 8 waves (2M x 4N).
// R11 schedule: glds16-only staging, triple buffer, stage 2 ahead,
// counted-vmcnt raw barriers (loads cross barriers in flight).
// Per wave per step glds: A {w0,w1:3, w2-7:2} + X 2 => vmcnt {5,5,4,...}.
// X staged raw f32 [32c][128t] with source-side 16B-chunk XOR swizzle;
// transposed ds_read_b32 (max 2-way bank alias = free) + in-reg bf16 cvt.
// ---------------------------------------------------------------------------
__global__ __launch_bounds__(512, 2) void k_main(const float* __restrict__ X,
                                                 const int* __restrict__ subj,
                                                 const u16* __restrict__ Wf,
                                                 float* __restrict__ out)
{
    __shared__ u16   Am[3][9216];    // [kq:4][288][8] bf16, 18KB each
    __shared__ float Xm[3][4096];    // [c:32][t:128] f32 (swizzled), 16KB each
    const int tid = threadIdx.x, lane = tid & 63, wid = tid >> 6;
    const int wm = wid >> 2, wn = wid & 3;
    const int hw = blockIdx.x;                 // 0..2047
    const int w  = (hw & 7) * 256 + (hw >> 3); // bijection, 256 blocks/XCD
    const int b  = w >> 4, nt = w & 15;
    const int t0 = nt * 128;
    const int s = subj[b];
    const float* Xb = X + (size_t)b * CIN * TT;
    const u16* WfA = Wf + (size_t)s * WF_PER_S;
    const int g = lane >> 4, l15 = lane & 15;  // kq group 0..3

    f32x4 acc[9][2];
#pragma unroll
    for (int i = 0; i < 9; ++i)
#pragma unroll
        for (int j = 0; j < 2; ++j) acc[i][j] = (f32x4){0.f, 0.f, 0.f, 0.f};

    // A: 18 segs x 1KB; waves 0,1: 3 glds; waves 2-7: 2 glds
#define STAGEA(KS, BUF)                                                     \
    {                                                                       \
        _Pragma("unroll")                                                   \
        for (int k3 = 0; k3 < 3; ++k3) {                                    \
            const int seg = wid + 8 * k3;                                   \
            if (seg < 18)                                                   \
                glds16(WfA + (size_t)(KS) * WF_PER_KS + seg * 512 + lane * 8,\
                       &Am[BUF][seg * 512]);                                \
        }                                                                   \
    }
    // X: 16 segs x 1KB (2 rows of 128 f32 each); wave w stages segs 2w,2w+1.
    // Source chunk XOR-swizzled so transposed read is bank-clean; row clamped.
#define STAGEX(KS, BUF)                                                     \
    {                                                                       \
        _Pragma("unroll")                                                   \
        for (int k2 = 0; k2 < 2; ++k2) {                                    \
            const int seg = wid * 2 + k2;                                   \
            const int cr0 = (KS) * 32 + seg * 2 + (lane >> 5);              \
            const int cr  = (cr0 < CIN) ? cr0 : (CIN - 1);                  \
            const int sc  = (lane & 31) ^ (((seg >> 2) & 3) << 2);          \
            glds16(Xb + (size_t)cr * TT + t0 + sc * 4,                      \
                   &Xm[BUF][seg * 256]);                                    \
        }                                                                   \
    }
    // this wave's per-step glds count as vmcnt immediate
#define WAITSTEP()  { if (wid < 2) WAITV(5); else WAITV(4); }

    // Build 2 B-frags from Xm (transposed read, <=2-way banks, bf16 cvt in-reg)
#define COMPUTE(BUF, LAST)                                                  \
    {                                                                       \
        const float* Xc = &Xm[BUF][0];                                      \
        bf16x8 bfr[2];                                                      \
        _Pragma("unroll")                                                   \
        for (int j = 0; j < 2; ++j) {                                       \
            const int tsw = (wn * 32 + j * 16 + l15) ^ (g << 4);            \
            bf16x8 bb;                                                      \
            _Pragma("unroll")                                               \
            for (int q = 0; q < 8; ++q) {                                   \
                float v = Xc[(g * 8 + q) * 128 + tsw];                      \
                if (LAST) {                                                 \
                    if (q == 7)      v = (g == 0) ? 1.0f : 0.0f;            \
                    else if (g > 0)  v = 0.0f;                              \
                }                                                           \
                bb[q] = (short)f2bf(v);                                     \
            }                                                               \
            bfr[j] = bb;                                                    \
        }                                                                   \
        _Pragma("unroll")                                                   \
        for (int i = 0; i < 9; ++i) {                                       \
            const bf16x8 af = *(const bf16x8*)(&Am[BUF][g * 2304 + (wm * 144 + i * 16 + l15) * 8]); \
            acc[i][0] = __builtin_amdgcn_mfma_f32_16x16x32_bf16(af, bfr[0], acc[i][0], 0, 0, 0); \
            acc[i][1] = __builtin_amdgcn_mfma_f32_16x16x32_bf16(af, bfr[1], acc[i][1], 0, 0, 0); \
        }                                                                   \
    }

    // ---- prologue: issue S0, S1; wait S0 only (S1 crosses the barrier) ----
    STAGEA(0, 0); STAGEX(0, 0); SB();
    STAGEA(1, 1); STAGEX(1, 1); SB();
    WAITSTEP();
    BAR();

    // ---- steady steps k=0..7: issue S(k+2); compute k; wait S(k+1) ----
#define STEP(K)                                                             \
    {                                                                       \
        STAGEA((K) + 2, ((K) + 2) % 3); STAGEX((K) + 2, ((K) + 2) % 3); SB();\
        COMPUTE((K) % 3, 0);                                                \
        WAITSTEP();                                                         \
        BAR();                                                              \
    }
    STEP(0) STEP(1) STEP(2) STEP(3) STEP(4) STEP(5) STEP(6) STEP(7)
    // ---- step 8: nothing left to stage; drain S9 ----
    COMPUTE(2, 0);
    WAITV(0);
    BAR();
    // ---- step 9 (bias/pad column handled in-register) ----
    COMPUTE(0, 1);

    // epilogue: C/D layout col=lane&15, row=(lane>>4)*4+reg (bias fused in K)
    const int rb = g * 4;
#pragma unroll
    for (int i = 0; i < 9; ++i) {
#pragma unroll
        for (int r = 0; r < 4; ++r) {
            const int e = wm * 144 + i * 16 + rb + r;
            if (e < DD) {
#pragma unroll
                for (int j = 0; j < 2; ++j) {
                    const int t = t0 + wn * 32 + j * 16 + l15;
                    out[((size_t)b * DD + e) * TT + t] = acc[i][j][r];
                }
            }
        }
    }
#undef STAGEA
#undef STAGEX
#undef WAITSTEP
#undef COMPUTE
#undef STEP
}

extern "C" void kernel_launch(void* const* d_in, const int* in_sizes, int n_in,
                              void* d_out, int out_size, void* d_ws, size_t ws_size,
                              hipStream_t stream) {
    const float* X    = (const float*)d_in[0];
    const int*   subj = (const int*)d_in[1];
    const float* W1   = (const float*)d_in[2];
    const float* b1   = (const float*)d_in[3];
    const float* Ws   = (const float*)d_in[4];
    float* out = (float*)d_out;

    u16* Wf  = (u16*)d_ws;                                         // 11,796,480 B
    u16* W1t = (u16*)((char*)d_ws + (size_t)NSUBJ * WF_PER_S * 2); // + 184,320 B

    k_prep_w1<<<dim3(360), 256, 0, stream>>>(W1, b1, W1t);
    k_fuse_w<<<dim3(3, NSUBJ), 256, 0, stream>>>(Ws, W1t, Wf);
    k_main<<<dim3(TT / 128 * BB), 512, 0, stream>>>(X, subj, Wf, out);
}

// Round 13
// 179.839 us; speedup vs baseline: 1.3608x; 1.0105x over previous
//
#include <hip/hip_runtime.h>
#include <hip/hip_bf16.h>

#define NSUBJ 64
#define CIN   295
#define DD    270
#define TT    2048
#define BB    128

// Wf tiled layout: [s][ks:10][kq:4][m:288][k8:8]  (bf16, c = ks*32+kq*8+k8)
// column c==295 holds the fused bias (Ws@b1); B-side c==295 synthesized as 1.0
#define WF_PER_S  92160   // 10*4*288*8
#define WF_PER_KS 9216    // 4*288*8
// W1t tiled layout: [ks:9][kq:4][c:320][8] bf16 (d = ks*32+kq*8+k8), c=295 -> b1
#define W1T_PER_KS 10240  // 4*320*8

typedef __attribute__((ext_vector_type(8))) short bf16x8;
typedef __attribute__((ext_vector_type(4))) float f32x4;
typedef unsigned short u16;

__device__ __forceinline__ u16 f2bf(float f) {
    return __bfloat16_as_ushort(__float2bfloat16(f));   // RNE HW cvt
}

// async global->LDS, 16B/lane; lds dest = base + lane*16 (linear, wave-uniform base)
__device__ __forceinline__ void glds16(const void* g, void* lds_base) {
    __builtin_amdgcn_global_load_lds(
        (const __attribute__((address_space(1))) unsigned int*)g,
        (__attribute__((address_space(3))) unsigned int*)lds_base, 16, 0, 0);
}

#define WAITV(N) asm volatile("s_waitcnt vmcnt(" #N ")" ::: "memory")
#define BAR()    __builtin_amdgcn_s_barrier()
#define SB()     __builtin_amdgcn_sched_barrier(0)

// ---------------------------------------------------------------------------
// W1 [270][295] f32 (+ b1 as c=295) -> W1t bf16 tiled [ks][kq][c:320][8]
// ---------------------------------------------------------------------------
__global__ __launch_bounds__(256) void k_prep_w1(const float* __restrict__ W1,
                                                 const float* __restrict__ b1,
                                                 u16* __restrict__ W1t)
{
    const int idx = blockIdx.x * 256 + threadIdx.x;      // 92160 total
    const int ks = idx / W1T_PER_KS;
    const int r  = idx - ks * W1T_PER_KS;
    const int kq = r / 2560;
    const int c  = (r - kq * 2560) >> 3;   // 0..319
    const int k8 = r & 7;
    const int d  = ks * 32 + kq * 8 + k8;
    float v = 0.f;
    if (d < DD) {
        if (c < CIN) v = W1[d * CIN + c];
        else if (c == CIN) v = b1[d];
    }
    W1t[idx] = f2bf(v);
}

// ---------------------------------------------------------------------------
// Wf[s] = bf16(Ws[s] @ [W1|b1]) in k_main's tiled A layout
// grid (3 mt, 64 s), block 256 = 4 waves (2M x 2N), tile 96e x 320c, K=288
// ---------------------------------------------------------------------------
__global__ __launch_bounds__(256, 1) void k_fuse_w(const float* __restrict__ Ws,
                                                   const u16* __restrict__ W1t,
                                                   u16* __restrict__ Wf)
{
    __shared__ u16 Aw[3072];    // [kq:4][96][8]
    __shared__ u16 Bw[10240];   // [kq:4][320][8]
    const int tid = threadIdx.x, lane = tid & 63, wid = tid >> 6;
    const int wm = wid >> 1, wn = wid & 1;
    const int mt = blockIdx.x, s = blockIdx.y;
    const int e0 = mt * 96;
    const float* Wsb = Ws + (size_t)s * DD * DD;

    f32x4 acc[3][10];
#pragma unroll
    for (int i = 0; i < 3; ++i)
#pragma unroll
        for (int j = 0; j < 10; ++j) acc[i][j] = (f32x4){0.f, 0.f, 0.f, 0.f};

    for (int ks = 0; ks < 9; ++ks) {
        const int k0 = ks * 32;
#pragma unroll
        for (int ci = 0; ci < 3; ++ci) {
            const int id = tid + ci * 256;
            const int m = id >> 3, q = id & 7;
            const int e = e0 + m, d = k0 + q * 4;
            float2 v01 = {0.f, 0.f}, v23 = {0.f, 0.f};
            if (e < DD) {
                if (d < DD)     v01 = *(const float2*)(Wsb + (size_t)e * DD + d);
                if (d + 2 < DD) v23 = *(const float2*)(Wsb + (size_t)e * DD + d + 2);
            }
            ushort4 h;
            h.x = f2bf(v01.x); h.y = f2bf(v01.y); h.z = f2bf(v23.x); h.w = f2bf(v23.y);
            *(ushort4*)(&Aw[(q >> 1) * 768 + m * 8 + (q & 1) * 4]) = h;
        }
#pragma unroll
        for (int k5 = 0; k5 < 5; ++k5) {
            const int seg = wid * 5 + k5;
            glds16(W1t + (size_t)ks * W1T_PER_KS + seg * 512 + lane * 8, &Bw[seg * 512]);
        }
        __syncthreads();
        bf16x8 af[3];
#pragma unroll
        for (int i = 0; i < 3; ++i)
            af[i] = *(const bf16x8*)(&Aw[(lane >> 4) * 768 + (wm * 48 + i * 16 + (lane & 15)) * 8]);
#pragma unroll
        for (int j = 0; j < 10; ++j) {
            const bf16x8 bfj = *(const bf16x8*)(&Bw[(lane >> 4) * 2560 + (wn * 160 + j * 16 + (lane & 15)) * 8]);
#pragma unroll
            for (int i = 0; i < 3; ++i)
                acc[i][j] = __builtin_amdgcn_mfma_f32_16x16x32_bf16(af[i], bfj, acc[i][j], 0, 0, 0);
        }
        __syncthreads();
    }
    const int rb = (lane >> 4) * 4, cc = lane & 15;
#pragma unroll
    for (int i = 0; i < 3; ++i) {
#pragma unroll
        for (int r = 0; r < 4; ++r) {
            const int e = e0 + wm * 48 + i * 16 + rb + r;
#pragma unroll
            for (int j = 0; j < 10; ++j) {
                const int c = wn * 160 + j * 16 + cc;
                Wf[(size_t)s * WF_PER_S + (c >> 5) * WF_PER_KS + ((c >> 3) & 3) * 2304
                   + e * 8 + (c & 7)] = f2bf(acc[i][j][r]);
            }
        }
    }
}

// ---------------------------------------------------------------------------
// out[b] = Wf[subj[b]] @ [X[b]; 1]
// PERSISTENT blocks: grid 512 (2/CU, no tail), each runs 8 consecutive items
// w = (hw&7)*512 + (hw>>3)*8 + it  (XCD-chunked; 8 items share one b -> Wf
// becomes L2-hot after item 0).  R11 pipeline per item (glds16-only staging,
// triple LDS buffer, stage-2-ahead, counted-vmcnt raw barriers), with the
// stage-ahead CROSSING item boundaries: steps 8/9 of item i stage S0/S1 of
// item i+1; LDS buffer names rotate by 1 per item (10 = 1 mod 3).  Stores of
// item i are issued but NOT drained -- WAITV(63) retires next-item staging
// only (in-order queue => counted waits stay safe with stores outstanding);
// the store burst L2-acks under item i+1's first compute steps.
// Per wave per step glds: A {w0,w1:5, w2,w3:4} + X 2 => vmcnt {7,7,6,6}.
// ---------------------------------------------------------------------------
__global__ __launch_bounds__(256, 2) void k_main(const float* __restrict__ X,
                                                 const int* __restrict__ subj,
                                                 const u16* __restrict__ Wf,
                                                 float* __restrict__ out)
{
    __shared__ u16   AmBuf[3][9216];    // [kq:4][288][8] bf16, 18KB each
    __shared__ float XmBuf[3][2048];    // [c:32][t:64] f32 (swizzled), 8KB each
    const int tid = threadIdx.x, lane = tid & 63, wid = tid >> 6;
    const int wm = wid >> 1, wn = wid & 1;
    const int g = lane >> 4, l15 = lane & 15;   // kq group 0..3
    const int hw = blockIdx.x;                  // 0..511
    int w = (hw & 7) * 512 + (hw >> 3) * 8;     // first of this block's 8 items
    int b = w >> 5;
    int t0 = (w & 31) * 64;
    const float* Xb = X + (size_t)b * CIN * TT;
    const u16*  WfA = Wf + (size_t)subj[b] * WF_PER_S;

    u16   *amA = &AmBuf[0][0], *amB = &AmBuf[1][0], *amC = &AmBuf[2][0];
    float *xmA = &XmBuf[0][0], *xmB = &XmBuf[1][0], *xmC = &XmBuf[2][0];

    f32x4 acc[9][2];
#pragma unroll
    for (int i = 0; i < 9; ++i)
#pragma unroll
        for (int j = 0; j < 2; ++j) acc[i][j] = (f32x4){0.f, 0.f, 0.f, 0.f};

    // A: 18 segs x 1KB; waves 0,1: 5 glds; waves 2,3: 4 glds
#define STAGEA_TO(KS, DST, WFP)                                             \
    {                                                                       \
        _Pragma("unroll")                                                   \
        for (int k5 = 0; k5 < 5; ++k5) {                                    \
            const int seg = wid + 4 * k5;                                   \
            if (seg < 18)                                                   \
                glds16((WFP) + (size_t)(KS) * WF_PER_KS + seg * 512 + lane * 8,\
                       (DST) + seg * 512);                                  \
        }                                                                   \
    }
    // X: 8 segs x 1KB (4 rows of 64 f32); wave w stages segs 2w, 2w+1.
    // Per-lane source col pre-swizzled (16B-chunk XOR); row clamped to <295.
#define STAGEX_TO(KS, DST, XP, T0)                                          \
    {                                                                       \
        _Pragma("unroll")                                                   \
        for (int k2 = 0; k2 < 2; ++k2) {                                    \
            const int seg = wid * 2 + k2;                                   \
            const int cr0 = (KS) * 32 + seg * 4 + g;                        \
            const int cr  = (cr0 < CIN) ? cr0 : (CIN - 1);                  \
            const int sc  = l15 ^ (((seg >> 1) & 3) << 2);                  \
            glds16((XP) + (size_t)cr * TT + (T0) + sc * 4,                  \
                   (DST) + seg * 256);                                      \
        }                                                                   \
    }
#define WAITSTEP()  { if (wid < 2) WAITV(7); else WAITV(6); }

    // Build 2 B-frags from Xm (transposed read, 2-way banks, bf16 cvt in-reg)
#define COMPUTE_FROM(AM, XM, LAST)                                          \
    {                                                                       \
        bf16x8 bfr[2];                                                      \
        _Pragma("unroll")                                                   \
        for (int j = 0; j < 2; ++j) {                                       \
            const int tsw = (wn * 32 + j * 16 + l15) ^ (g << 4);            \
            bf16x8 bb;                                                      \
            _Pragma("unroll")                                               \
            for (int q = 0; q < 8; ++q) {                                   \
                float v = (XM)[(g * 8 + q) * 64 + tsw];                     \
                if (LAST) {                                                 \
                    if (q == 7)      v = (g == 0) ? 1.0f : 0.0f;            \
                    else if (g > 0)  v = 0.0f;                              \
                }                                                           \
                bb[q] = (short)f2bf(v);                                     \
            }                                                               \
            bfr[j] = bb;                                                    \
        }                                                                   \
        _Pragma("unroll")                                                   \
        for (int i = 0; i < 9; ++i) {                                       \
            const bf16x8 af = *(const bf16x8*)((AM) + g * 2304 + (wm * 144 + i * 16 + l15) * 8); \
            acc[i][0] = __builtin_amdgcn_mfma_f32_16x16x32_bf16(af, bfr[0], acc[i][0], 0, 0, 0); \
            acc[i][1] = __builtin_amdgcn_mfma_f32_16x16x32_bf16(af, bfr[1], acc[i][1], 0, 0, 0); \
        }                                                                   \
    }
    // steady step: stage S(K+2) of THIS item, compute K, retire S(K+1)
#define STEPN(K, DAM, DXM, CAM, CXM)                                        \
    {                                                                       \
        STAGEA_TO((K) + 2, DAM, WfA); STAGEX_TO((K) + 2, DXM, Xb, t0); SB();\
        COMPUTE_FROM(CAM, CXM, 0);                                          \
        WAITSTEP();                                                         \
        BAR();                                                              \
    }

    // ---- block prologue (once): stage S0->name0, S1->name1 ----
    STAGEA_TO(0, amA, WfA); STAGEX_TO(0, xmA, Xb, t0); SB();
    STAGEA_TO(1, amB, WfA); STAGEX_TO(1, xmB, Xb, t0); SB();
    WAITSTEP();
    BAR();

#pragma unroll 1
    for (int it = 0; it < 8; ++it) {
        const bool more = (it < 7);
        const int  w2  = more ? (w + 1) : w;
        const int  b2  = w2 >> 5;
        const int  t02 = (w2 & 31) * 64;
        const float* XbN = X + (size_t)b2 * CIN * TT;
        const u16*  WfAN = Wf + (size_t)subj[b2] * WF_PER_S;

        // steps 0..7: stage within item.  buffer name for step k = (k)%3,
        // staging target = (k+2)%3  (names already rotated to item phase)
        STEPN(0, amC, xmC, amA, xmA)
        STEPN(1, amA, xmA, amB, xmB)
        STEPN(2, amB, xmB, amC, xmC)
        STEPN(3, amC, xmC, amA, xmA)
        STEPN(4, amA, xmA, amB, xmB)
        STEPN(5, amB, xmB, amC, xmC)
        STEPN(6, amC, xmC, amA, xmA)
        STEPN(7, amA, xmA, amB, xmB)
        // step 8: stage NEXT item's S0 -> name1; compute 8 (name2)
        if (more) { STAGEA_TO(0, amB, WfAN); STAGEX_TO(0, xmB, XbN, t02); SB(); }
        COMPUTE_FROM(amC, xmC, 0);
        if (more) { WAITSTEP(); }       // retires S9; nS0 crosses barrier
        else      { WAITV(0); }         // last item: drain S9
        BAR();
        // step 9: stage NEXT item's S1 -> name2; compute 9 (name0, bias col)
        if (more) { STAGEA_TO(1, amC, WfAN); STAGEX_TO(1, xmC, XbN, t02); SB(); }
        COMPUTE_FROM(amA, xmA, 1);

        // ---- epilogue stores for this item (issued, not drained) ----
        {
            const int rb = g * 4;
#pragma unroll
            for (int i = 0; i < 9; ++i) {
#pragma unroll
                for (int r = 0; r < 4; ++r) {
                    const int e = wm * 144 + i * 16 + rb + r;
                    if (e < DD) {
#pragma unroll
                        for (int j = 0; j < 2; ++j) {
                            const int t = t0 + wn * 32 + j * 16 + l15;
                            out[((size_t)b * DD + e) * TT + t] = acc[i][j][r];
                        }
                    }
                }
            }
        }
        // reset accumulators for next item
#pragma unroll
        for (int i = 0; i < 9; ++i)
#pragma unroll
            for (int j = 0; j < 2; ++j) acc[i][j] = (f32x4){0.f, 0.f, 0.f, 0.f};

        if (more) {
            // retire nS0 (+nS1, + a few store-acks); stores keep draining
            // under next item's first compute steps.  63 = vmcnt max.
            WAITV(63);
            BAR();
            // rotate buffer names by 1 (10 steps = +1 mod 3)
            u16*   ta = amA; amA = amB; amB = amC; amC = ta;
            float* tx = xmA; xmA = xmB; xmB = xmC; xmC = tx;
            w = w2; b = b2; t0 = t02; Xb = XbN; WfA = WfAN;
        }
    }
#undef STAGEA_TO
#undef STAGEX_TO
#undef WAITSTEP
#undef COMPUTE_FROM
#undef STEPN
}

extern "C" void kernel_launch(void* const* d_in, const int* in_sizes, int n_in,
                              void* d_out, int out_size, void* d_ws, size_t ws_size,
                              hipStream_t stream) {
    const float* X    = (const float*)d_in[0];
    const int*   subj = (const int*)d_in[1];
    const float* W1   = (const float*)d_in[2];
    const float* b1   = (const float*)d_in[3];
    const float* Ws   = (const float*)d_in[4];
    float* out = (float*)d_out;

    u16* Wf  = (u16*)d_ws;                                         // 11,796,480 B
    u16* W1t = (u16*)((char*)d_ws + (size_t)NSUBJ * WF_PER_S * 2); // + 184,320 B

    k_prep_w1<<<dim3(360), 256, 0, stream>>>(W1, b1, W1t);
    k_fuse_w<<<dim3(3, NSUBJ), 256, 0, stream>>>(Ws, W1t, Wf);
    k_main<<<dim3(512), 256, 0, stream>>>(X, subj, Wf, out);
}